// Round 8
// baseline (216.401 us; speedup 1.0000x reference)
//
#include <hip/hip_runtime.h>

#define HD 64   // hidden dim D

// ---- fast zero ----
__global__ void zero_kernel(int4* __restrict__ p, int n4) {
    int i = blockIdx.x * blockDim.x + threadIdx.x;
    if (i < n4) p[i] = int4{0, 0, 0, 0};
}

// ---- degree histogram, dst-range partitioned: group g = blockIdx&7 owns dst slice
// [g*N/8,(g+1)*N/8) so deg lines stay in ONE XCD's L2 (no cross-XCD atomic line thrash).
__global__ void deg_part_kernel(const int* __restrict__ dst, int* __restrict__ deg,
                                int E, int N) {
    const int g = blockIdx.x & 7;
    const int per = (N + 7) / 8;
    const int lo = g * per;
    const int hi = min(N, lo + per);
    const int nb = gridDim.x >> 3;
    const int b = blockIdx.x >> 3;
    for (int e = b * blockDim.x + threadIdx.x; e < E; e += nb * blockDim.x) {
        int d = dst[e];
        if (d >= lo && d < hi) atomicAdd(&deg[d], 1);
    }
}

// ---- per-block local exclusive scan of deg ----
__global__ __launch_bounds__(1024) void scanA_kernel(const int* __restrict__ deg,
                                                     int* __restrict__ excl,
                                                     int* __restrict__ bsum, int N) {
    const int tid = threadIdx.x, lane = tid & 63, wid = tid >> 6;
    const int i = blockIdx.x * 1024 + tid;
    int v = (i < N) ? deg[i] : 0;
    int s = v;
#pragma unroll
    for (int off = 1; off < 64; off <<= 1) {
        int t = __shfl_up(s, off, 64);
        if (lane >= off) s += t;
    }
    __shared__ int wtot[16], woff[16];
    if (lane == 63) wtot[wid] = s;
    __syncthreads();
    if (wid == 0 && lane < 16) {
        int t = wtot[lane];
        int ss = t;
#pragma unroll
        for (int off = 1; off < 16; off <<= 1) {
            int u = __shfl_up(ss, off, 64);
            if (lane >= off) ss += u;
        }
        woff[lane] = ss - t;
        if (lane == 15) bsum[blockIdx.x] = ss;
    }
    __syncthreads();
    if (i < N) excl[i] = woff[wid] + (s - v);
}

// ---- apply: scans bsum (NB<=64) in-wave per block ----
__global__ __launch_bounds__(1024) void scanC_kernel(const int* __restrict__ excl,
                                                     const int* __restrict__ bsum,
                                                     const int* __restrict__ deg,
                                                     int* __restrict__ row_start,
                                                     int* __restrict__ cursor,
                                                     float* __restrict__ inv_deg,
                                                     int N, int E, int NB) {
    __shared__ int boff_s;
    const int tid = threadIdx.x;
    if (tid < 64) {
        int lane = tid;
        int v = (lane < NB) ? bsum[lane] : 0;
        int s = v;
#pragma unroll
        for (int off = 1; off < 64; off <<= 1) {
            int t = __shfl_up(s, off, 64);
            if (lane >= off) s += t;
        }
        if (lane == (int)blockIdx.x) boff_s = s - v;
    }
    __syncthreads();
    const int boff = boff_s;
    int i = blockIdx.x * 1024 + tid;
    if (i < N) {
        int e = excl[i] + boff;
        row_start[i] = e;
        cursor[i] = e;
        int d = deg[i];
        inv_deg[i] = (d > 0) ? 1.0f / (float)d : 0.0f;
    }
    if (blockIdx.x == 0 && tid == 0) row_start[N] = E;
}

// ---- CSR fill, dst-range partitioned ----
__global__ void fill_part_kernel(const int* __restrict__ src, const int* __restrict__ dst,
                                 int* __restrict__ cursor, int* __restrict__ csr,
                                 int E, int N) {
    const int g = blockIdx.x & 7;
    const int per = (N + 7) / 8;
    const int lo = g * per;
    const int hi = min(N, lo + per);
    const int nb = gridDim.x >> 3;
    const int b = blockIdx.x >> 3;
    for (int e = b * blockDim.x + threadIdx.x; e < E; e += nb * blockDim.x) {
        int d = dst[e];
        if (d >= lo && d < hi) {
            int p = atomicAdd(&cursor[d], 1);
            csr[p] = src[e];
        }
    }
}

// ---- aggregate: wave per node, lane = feature dim; mean of neighbor rows ----
__global__ __launch_bounds__(256, 8) void agg_kernel(
    const float* __restrict__ h, const int* __restrict__ row_start,
    const int* __restrict__ csr, const float* __restrict__ inv_deg,
    float* __restrict__ neigh, int N) {
    const int wv = (blockIdx.x * blockDim.x + threadIdx.x) >> 6;
    const int lane = threadIdx.x & 63;
    if (wv >= N) return;
    const int rs = row_start[wv];
    const int re = row_start[wv + 1];

    float a0 = 0.f, a1 = 0.f, a2 = 0.f, a3 = 0.f;
    float a4 = 0.f, a5 = 0.f, a6 = 0.f, a7 = 0.f;
    int j = rs;
    while (j < re) {
        int take = re - j;
        if (take > 64) take = 64;
        int idx = (lane < take) ? csr[j + lane] : 0;
        int i = 0;
        for (; i + 8 <= take; i += 8) {
            int s0 = __builtin_amdgcn_readlane(idx, i + 0);
            int s1 = __builtin_amdgcn_readlane(idx, i + 1);
            int s2 = __builtin_amdgcn_readlane(idx, i + 2);
            int s3 = __builtin_amdgcn_readlane(idx, i + 3);
            int s4 = __builtin_amdgcn_readlane(idx, i + 4);
            int s5 = __builtin_amdgcn_readlane(idx, i + 5);
            int s6 = __builtin_amdgcn_readlane(idx, i + 6);
            int s7 = __builtin_amdgcn_readlane(idx, i + 7);
            a0 += h[(long long)s0 * HD + lane];
            a1 += h[(long long)s1 * HD + lane];
            a2 += h[(long long)s2 * HD + lane];
            a3 += h[(long long)s3 * HD + lane];
            a4 += h[(long long)s4 * HD + lane];
            a5 += h[(long long)s5 * HD + lane];
            a6 += h[(long long)s6 * HD + lane];
            a7 += h[(long long)s7 * HD + lane];
        }
        for (; i < take; ++i) {
            int s0 = __builtin_amdgcn_readlane(idx, i);
            a0 += h[(long long)s0 * HD + lane];
        }
        j += take;
    }
    float m = (((a0 + a1) + (a2 + a3)) + ((a4 + a5) + (a6 + a7))) * inv_deg[wv];
    neigh[(long long)wv * HD + lane] = m;
}

// ---- GEMM + relu + L2-norm: out = l2norm(relu([h|neigh] @ W^T)) ----
// 512 threads (8 waves), 64 nodes/block, 8 nodes/wave; lane = output dim.
// W TRANSPOSED in LDS: Wl[j4][row] -> read Wl[j4*64+lane] is stride-1 per-lane
// ds_read_b128, conflict-free (round-7 counter: 800K conflicts from the old
// row-major layout whose 512B row stride collapsed 64 lanes onto 8 bank groups).
// LDS 64KB -> 2 blocks/CU x 8 waves = 16 waves/CU. In-place safe.
__global__ __launch_bounds__(512) void gemm_kernel(
    const float* __restrict__ h, const float* __restrict__ neigh,
    const float* __restrict__ W, float* __restrict__ out, int N) {
    __shared__ float4 Wl[32 * 64];     // 32 KB, [j4][row]
    __shared__ float4 Z[64 * 32];      // 32 KB, [node][j4]
    const int tid = threadIdx.x;
    const int lane = tid & 63;
    const int w = tid >> 6;
    const int base = blockIdx.x * 64;

    // stage W transposed: coalesced global read, strided LDS store (one-time cost)
    for (int t = tid; t < 2048; t += 512) {
        int row = t >> 5;
        int j4 = t & 31;
        Wl[j4 * 64 + row] = ((const float4*)W)[t];
    }
    // stage Z = [h | neigh] for 64 nodes — coalesced
    for (int t = tid; t < 1024; t += 512) {
        int n = t >> 4;
        int j4 = t & 15;
        int node = base + n;
        if (node < N) {
            Z[n * 32 + j4]      = ((const float4*)&h[(long long)node * HD])[j4];
            Z[n * 32 + 16 + j4] = ((const float4*)&neigh[(long long)node * HD])[j4];
        }
    }
    __syncthreads();

    float acc[8] = {0.f, 0.f, 0.f, 0.f, 0.f, 0.f, 0.f, 0.f};
    const int nb = w * 8;              // this wave's 8 nodes
#pragma unroll 2                        // cap unroll (round-3 lesson: avoid spill)
    for (int j4 = 0; j4 < 32; ++j4) {
        float4 wv = Wl[j4 * 64 + lane];          // stride-1, conflict-free
#pragma unroll
        for (int n = 0; n < 8; ++n) {
            float4 z = Z[(nb + n) * 32 + j4];    // wave-uniform broadcast
            acc[n] = fmaf(z.x, wv.x, fmaf(z.y, wv.y, fmaf(z.z, wv.z, fmaf(z.w, wv.w, acc[n]))));
        }
    }

#pragma unroll
    for (int n = 0; n < 8; ++n) {
        float v = fmaxf(acc[n], 0.f);
        float sq = v * v;
#pragma unroll
        for (int off = 32; off >= 1; off >>= 1) sq += __shfl_xor(sq, off, 64);
        float sc = 1.f / fmaxf(sqrtf(sq), 1e-12f);
        int node = base + nb + n;
        if (node < N) out[(long long)node * HD + lane] = v * sc;
    }
}

extern "C" void kernel_launch(void* const* d_in, const int* in_sizes, int n_in,
                              void* d_out, int out_size, void* d_ws, size_t ws_size,
                              hipStream_t stream) {
    const float* x    = (const float*)d_in[0];
    const float* W    = (const float*)d_in[1];
    const int*   esrc = (const int*)d_in[2];
    const int*   edst = (const int*)d_in[3];
    float* out = (float*)d_out;

    const int N = in_sizes[0] / HD;
    const int E = in_sizes[2];
    const int DEPTH = in_sizes[1] / (HD * 2 * HD);
    const int NB = (N + 1023) / 1024;

    auto align256 = [](size_t v) { return (v + 255) & ~(size_t)255; };
    char* ws = (char*)d_ws;
    int*   deg       = (int*)ws;    ws += align256((size_t)(N + 4) * 4);
    int*   excl      = (int*)ws;    ws += align256((size_t)N * 4);
    int*   bsum      = (int*)ws;    ws += align256(64 * 4);
    int*   row_start = (int*)ws;    ws += align256((size_t)(N + 1) * 4);
    int*   cursor    = (int*)ws;    ws += align256((size_t)N * 4);
    float* inv_deg   = (float*)ws;  ws += align256((size_t)N * 4);
    int*   csr       = (int*)ws;    ws += align256((size_t)E * 4);
    float* neigh     = (float*)ws;

    int n4 = (N + 3) / 4;
    zero_kernel<<<(n4 + 255) / 256, 256, 0, stream>>>((int4*)deg, n4);
    deg_part_kernel<<<2048, 256, 0, stream>>>(edst, deg, E, N);
    scanA_kernel<<<NB, 1024, 0, stream>>>(deg, excl, bsum, N);
    scanC_kernel<<<NB, 1024, 0, stream>>>(excl, bsum, deg, row_start, cursor, inv_deg, N, E, NB);
    fill_part_kernel<<<2048, 256, 0, stream>>>(esrc, edst, cursor, csr, E, N);

    const float* h_in = x;
    for (int k = 0; k < DEPTH; ++k) {
        agg_kernel<<<(N * 64 + 255) / 256, 256, 0, stream>>>(h_in, row_start, csr, inv_deg, neigh, N);
        gemm_kernel<<<(N + 63) / 64, 512, 0, stream>>>(h_in, neigh,
                                                       W + (size_t)k * HD * 2 * HD, out, N);
        h_in = out;   // gemm is in-place safe
    }
}

// Round 9
// 173.455 us; speedup vs baseline: 1.2476x; 1.2476x over previous
//
#include <hip/hip_runtime.h>

#define HD 64   // hidden dim D

typedef short  bf16x8 __attribute__((ext_vector_type(8)));
typedef float  f32x4  __attribute__((ext_vector_type(4)));

__device__ inline float bf2f(ushort u) {
    unsigned x = ((unsigned)u) << 16;
    return __builtin_bit_cast(float, x);
}
__device__ inline ushort f2bf(float f) {   // round-to-nearest-even
    unsigned u = __builtin_bit_cast(unsigned, f);
    u += 0x7fffu + ((u >> 16) & 1u);
    return (ushort)(u >> 16);
}

// ---- fast zero ----
__global__ void zero_kernel(int4* __restrict__ p, int n4) {
    int i = blockIdx.x * blockDim.x + threadIdx.x;
    if (i < n4) p[i] = int4{0, 0, 0, 0};
}

// ---- f32 -> bf16 bulk convert (x, W) ----
__global__ void f2bf4_kernel(const float4* __restrict__ in, ushort4* __restrict__ ob, int n4) {
    int i = blockIdx.x * blockDim.x + threadIdx.x;
    if (i < n4) {
        float4 v = in[i];
        ushort4 o;
        o.x = f2bf(v.x); o.y = f2bf(v.y); o.z = f2bf(v.z); o.w = f2bf(v.w);
        ob[i] = o;
    }
}

// ---- degree histogram, dst-range partitioned (XCD-local atomic lines) ----
__global__ void deg_part_kernel(const int* __restrict__ dst, int* __restrict__ deg,
                                int E, int N) {
    const int g = blockIdx.x & 7;
    const int per = (N + 7) / 8;
    const int lo = g * per;
    const int hi = min(N, lo + per);
    const int nb = gridDim.x >> 3;
    const int b = blockIdx.x >> 3;
    for (int e = b * blockDim.x + threadIdx.x; e < E; e += nb * blockDim.x) {
        int d = dst[e];
        if (d >= lo && d < hi) atomicAdd(&deg[d], 1);
    }
}

// ---- per-block local exclusive scan of deg ----
__global__ __launch_bounds__(1024) void scanA_kernel(const int* __restrict__ deg,
                                                     int* __restrict__ excl,
                                                     int* __restrict__ bsum, int N) {
    const int tid = threadIdx.x, lane = tid & 63, wid = tid >> 6;
    const int i = blockIdx.x * 1024 + tid;
    int v = (i < N) ? deg[i] : 0;
    int s = v;
#pragma unroll
    for (int off = 1; off < 64; off <<= 1) {
        int t = __shfl_up(s, off, 64);
        if (lane >= off) s += t;
    }
    __shared__ int wtot[16], woff[16];
    if (lane == 63) wtot[wid] = s;
    __syncthreads();
    if (wid == 0 && lane < 16) {
        int t = wtot[lane];
        int ss = t;
#pragma unroll
        for (int off = 1; off < 16; off <<= 1) {
            int u = __shfl_up(ss, off, 64);
            if (lane >= off) ss += u;
        }
        woff[lane] = ss - t;
        if (lane == 15) bsum[blockIdx.x] = ss;
    }
    __syncthreads();
    if (i < N) excl[i] = woff[wid] + (s - v);
}

// ---- apply: scans bsum (NB<=64) in-wave per block ----
__global__ __launch_bounds__(1024) void scanC_kernel(const int* __restrict__ excl,
                                                     const int* __restrict__ bsum,
                                                     const int* __restrict__ deg,
                                                     int* __restrict__ row_start,
                                                     int* __restrict__ cursor,
                                                     float* __restrict__ inv_deg,
                                                     int N, int E, int NB) {
    __shared__ int boff_s;
    const int tid = threadIdx.x;
    if (tid < 64) {
        int lane = tid;
        int v = (lane < NB) ? bsum[lane] : 0;
        int s = v;
#pragma unroll
        for (int off = 1; off < 64; off <<= 1) {
            int t = __shfl_up(s, off, 64);
            if (lane >= off) s += t;
        }
        if (lane == (int)blockIdx.x) boff_s = s - v;
    }
    __syncthreads();
    const int boff = boff_s;
    int i = blockIdx.x * 1024 + tid;
    if (i < N) {
        int e = excl[i] + boff;
        row_start[i] = e;
        cursor[i] = e;
        int d = deg[i];
        inv_deg[i] = (d > 0) ? 1.0f / (float)d : 0.0f;
    }
    if (blockIdx.x == 0 && tid == 0) row_start[N] = E;
}

// ---- CSR fill, dst-range partitioned ----
__global__ void fill_part_kernel(const int* __restrict__ src, const int* __restrict__ dst,
                                 int* __restrict__ cursor, int* __restrict__ csr,
                                 int E, int N) {
    const int g = blockIdx.x & 7;
    const int per = (N + 7) / 8;
    const int lo = g * per;
    const int hi = min(N, lo + per);
    const int nb = gridDim.x >> 3;
    const int b = blockIdx.x >> 3;
    for (int e = b * blockDim.x + threadIdx.x; e < E; e += nb * blockDim.x) {
        int d = dst[e];
        if (d >= lo && d < hi) {
            int p = atomicAdd(&cursor[d], 1);
            csr[p] = src[e];
        }
    }
}

// ---- aggregate: wave per node, lane = feature dim; mean of bf16 neighbor rows ----
// bf16 h halves the random-gather traffic vs f32 (round-8 insight).
__global__ __launch_bounds__(256, 8) void agg_kernel(
    const ushort* __restrict__ hb, const int* __restrict__ row_start,
    const int* __restrict__ csr, const float* __restrict__ inv_deg,
    ushort* __restrict__ neighb, int N) {
    const int wv = (blockIdx.x * blockDim.x + threadIdx.x) >> 6;
    const int lane = threadIdx.x & 63;
    if (wv >= N) return;
    const int rs = row_start[wv];
    const int re = row_start[wv + 1];

    float a0 = 0.f, a1 = 0.f, a2 = 0.f, a3 = 0.f;
    float a4 = 0.f, a5 = 0.f, a6 = 0.f, a7 = 0.f;
    int j = rs;
    while (j < re) {
        int take = re - j;
        if (take > 64) take = 64;
        int idx = (lane < take) ? csr[j + lane] : 0;
        int i = 0;
        for (; i + 8 <= take; i += 8) {
            int s0 = __builtin_amdgcn_readlane(idx, i + 0);
            int s1 = __builtin_amdgcn_readlane(idx, i + 1);
            int s2 = __builtin_amdgcn_readlane(idx, i + 2);
            int s3 = __builtin_amdgcn_readlane(idx, i + 3);
            int s4 = __builtin_amdgcn_readlane(idx, i + 4);
            int s5 = __builtin_amdgcn_readlane(idx, i + 5);
            int s6 = __builtin_amdgcn_readlane(idx, i + 6);
            int s7 = __builtin_amdgcn_readlane(idx, i + 7);
            ushort v0 = hb[(long long)s0 * HD + lane];
            ushort v1 = hb[(long long)s1 * HD + lane];
            ushort v2 = hb[(long long)s2 * HD + lane];
            ushort v3 = hb[(long long)s3 * HD + lane];
            ushort v4 = hb[(long long)s4 * HD + lane];
            ushort v5 = hb[(long long)s5 * HD + lane];
            ushort v6 = hb[(long long)s6 * HD + lane];
            ushort v7 = hb[(long long)s7 * HD + lane];
            a0 += bf2f(v0); a1 += bf2f(v1); a2 += bf2f(v2); a3 += bf2f(v3);
            a4 += bf2f(v4); a5 += bf2f(v5); a6 += bf2f(v6); a7 += bf2f(v7);
        }
        for (; i < take; ++i) {
            int s0 = __builtin_amdgcn_readlane(idx, i);
            a0 += bf2f(hb[(long long)s0 * HD + lane]);
        }
        j += take;
    }
    float m = (((a0 + a1) + (a2 + a3)) + ((a4 + a5) + (a6 + a7))) * inv_deg[wv];
    neighb[(long long)wv * HD + lane] = f2bf(m);
}

// ---- MFMA GEMM + relu + L2-norm: out = l2norm(relu([hb|neighb] @ Wb^T)) ----
// 256 thr / 4 waves; wave w owns 16 nodes (base+w*16..+15), all 64 out dims.
// Per wave: 4 K-steps x 4 N-tiles of mfma_f32_16x16x32_bf16, A/B frags loaded
// straight from global (16B/lane, L2-hit) -- no LDS in the hot loop (round-8:
// f32 path was LDS-issue bound at 288 ds_reads/wave).
// A frag: lane holds Z[node base+(l&15)][k=(l>>4)*8+0..7]; B frag: lane holds
// W[out t*16+(l&15)][k=(l>>4)*8+0..7]. C/D: col(out)=l&15, row(node)=(l>>4)*4+reg
// [m89-verified layout]. Norm = shfl_xor reduce over the 16-lane col group.
__global__ __launch_bounds__(256) void gemm_mfma_kernel(
    const ushort* __restrict__ hb, const ushort* __restrict__ nbf,
    const ushort* __restrict__ Wb, float* __restrict__ out,
    ushort* __restrict__ hb_out, int N, int last) {
    const int lane = threadIdx.x & 63;
    const int w = threadIdx.x >> 6;
    const int base = blockIdx.x * 64 + w * 16;
    const int m = lane & 15;          // A row / B col within tile
    const int kq = lane >> 4;         // k-quad
    int anode = base + m;
    if (anode > N - 1) anode = N - 1; // clamp (reads only; stores guarded)
    const long long arow = (long long)anode * HD;

    f32x4 acc[4] = {{0.f,0.f,0.f,0.f},{0.f,0.f,0.f,0.f},{0.f,0.f,0.f,0.f},{0.f,0.f,0.f,0.f}};
#pragma unroll
    for (int kk = 0; kk < 4; ++kk) {
        const ushort* ap = (kk < 2 ? hb : nbf) + arow + (kk & 1) * 32 + kq * 8;
        bf16x8 a = *(const bf16x8*)ap;
        const ushort* bp = Wb + (long long)m * 128 + kk * 32 + kq * 8;
#pragma unroll
        for (int t = 0; t < 4; ++t) {
            bf16x8 b = *(const bf16x8*)(bp + (long long)t * 16 * 128);
            acc[t] = __builtin_amdgcn_mfma_f32_16x16x32_bf16(a, b, acc[t], 0, 0, 0);
        }
    }

    // relu + per-node (row) sum of squares
    float sq[4] = {0.f, 0.f, 0.f, 0.f};
#pragma unroll
    for (int t = 0; t < 4; ++t)
#pragma unroll
        for (int r = 0; r < 4; ++r) {
            float v = fmaxf(acc[t][r], 0.f);
            acc[t][r] = v;
            sq[r] += v * v;
        }
    // reduce across the 16 lanes (cols) sharing this kq
#pragma unroll
    for (int off = 1; off < 16; off <<= 1)
#pragma unroll
        for (int r = 0; r < 4; ++r) sq[r] += __shfl_xor(sq[r], off, 64);

    float scl[4];
#pragma unroll
    for (int r = 0; r < 4; ++r) scl[r] = 1.f / fmaxf(sqrtf(sq[r]), 1e-12f);

    if (last) {
#pragma unroll
        for (int r = 0; r < 4; ++r) {
            int node = base + kq * 4 + r;
            if (node < N) {
#pragma unroll
                for (int t = 0; t < 4; ++t)
                    out[(long long)node * HD + t * 16 + m] = acc[t][r] * scl[r];
            }
        }
    } else {
#pragma unroll
        for (int r = 0; r < 4; ++r) {
            int node = base + kq * 4 + r;
            if (node < N) {
#pragma unroll
                for (int t = 0; t < 4; ++t)
                    hb_out[(long long)node * HD + t * 16 + m] = f2bf(acc[t][r] * scl[r]);
            }
        }
    }
}

extern "C" void kernel_launch(void* const* d_in, const int* in_sizes, int n_in,
                              void* d_out, int out_size, void* d_ws, size_t ws_size,
                              hipStream_t stream) {
    const float* x    = (const float*)d_in[0];
    const float* W    = (const float*)d_in[1];
    const int*   esrc = (const int*)d_in[2];
    const int*   edst = (const int*)d_in[3];
    float* out = (float*)d_out;

    const int N = in_sizes[0] / HD;
    const int E = in_sizes[2];
    const int DEPTH = in_sizes[1] / (HD * 2 * HD);
    const int NB = (N + 1023) / 1024;

    // ws: deg | excl | bsum | row_start | cursor | inv_deg | csr | hb0 | hb1 | neighb | Wb
    auto align256 = [](size_t v) { return (v + 255) & ~(size_t)255; };
    char* ws = (char*)d_ws;
    int*    deg       = (int*)ws;     ws += align256((size_t)(N + 4) * 4);
    int*    excl      = (int*)ws;     ws += align256((size_t)N * 4);
    int*    bsum      = (int*)ws;     ws += align256(64 * 4);
    int*    row_start = (int*)ws;     ws += align256((size_t)(N + 1) * 4);
    int*    cursor    = (int*)ws;     ws += align256((size_t)N * 4);
    float*  inv_deg   = (float*)ws;   ws += align256((size_t)N * 4);
    int*    csr       = (int*)ws;     ws += align256((size_t)E * 4);
    ushort* hb0       = (ushort*)ws;  ws += align256((size_t)N * HD * 2);
    ushort* hb1       = (ushort*)ws;  ws += align256((size_t)N * HD * 2);
    ushort* neighb    = (ushort*)ws;  ws += align256((size_t)N * HD * 2);
    ushort* Wb        = (ushort*)ws;

    // CSR build
    int n4 = (N + 3) / 4;
    zero_kernel<<<(n4 + 255) / 256, 256, 0, stream>>>((int4*)deg, n4);
    deg_part_kernel<<<2048, 256, 0, stream>>>(edst, deg, E, N);
    scanA_kernel<<<NB, 1024, 0, stream>>>(deg, excl, bsum, N);
    scanC_kernel<<<NB, 1024, 0, stream>>>(excl, bsum, deg, row_start, cursor, inv_deg, N, E, NB);
    fill_part_kernel<<<2048, 256, 0, stream>>>(esrc, edst, cursor, csr, E, N);

    // bf16 conversions: x -> hb0, W -> Wb
    int xn4 = N * HD / 4;
    f2bf4_kernel<<<(xn4 + 255) / 256, 256, 0, stream>>>((const float4*)x, (ushort4*)hb0, xn4);
    int wn4 = DEPTH * HD * 2 * HD / 4;
    f2bf4_kernel<<<(wn4 + 255) / 256, 256, 0, stream>>>((const float4*)W, (ushort4*)Wb, wn4);

    ushort* hb_cur = hb0;
    ushort* hb_nxt = hb1;
    for (int k = 0; k < DEPTH; ++k) {
        int last = (k == DEPTH - 1) ? 1 : 0;
        agg_kernel<<<(N * 64 + 255) / 256, 256, 0, stream>>>(hb_cur, row_start, csr,
                                                             inv_deg, neighb, N);
        gemm_mfma_kernel<<<(N + 63) / 64, 256, 0, stream>>>(hb_cur, neighb,
                                                            Wb + (size_t)k * HD * 2 * HD,
                                                            out, hb_nxt, N, last);
        ushort* t = hb_cur; hb_cur = hb_nxt; hb_nxt = t;
    }
}

// Round 10
// 157.737 us; speedup vs baseline: 1.3719x; 1.0996x over previous
//
#include <hip/hip_runtime.h>

#define HD 64   // hidden dim D

typedef short  bf16x8 __attribute__((ext_vector_type(8)));
typedef float  f32x4  __attribute__((ext_vector_type(4)));

__device__ inline float bf2f(ushort u) {
    unsigned x = ((unsigned)u) << 16;
    return __builtin_bit_cast(float, x);
}
__device__ inline ushort f2bf(float f) {   // round-to-nearest-even
    unsigned u = __builtin_bit_cast(unsigned, f);
    u += 0x7fffu + ((u >> 16) & 1u);
    return (ushort)(u >> 16);
}

// ---- fused prep: zero deg | f2bf(x) | f2bf(W)  (3 launches -> 1) ----
__global__ void prep_kernel(const float4* __restrict__ x, ushort4* __restrict__ hb, int xn4,
                            const float4* __restrict__ W, ushort4* __restrict__ Wb, int wn4,
                            int4* __restrict__ deg4, int dn4) {
    int i = blockIdx.x * blockDim.x + threadIdx.x;
    if (i < xn4) {
        float4 v = x[i];
        ushort4 o; o.x = f2bf(v.x); o.y = f2bf(v.y); o.z = f2bf(v.z); o.w = f2bf(v.w);
        hb[i] = o;
        return;
    }
    int j = i - xn4;
    if (j < wn4) {
        float4 v = W[j];
        ushort4 o; o.x = f2bf(v.x); o.y = f2bf(v.y); o.z = f2bf(v.z); o.w = f2bf(v.w);
        Wb[j] = o;
        return;
    }
    int k = j - wn4;
    if (k < dn4) deg4[k] = int4{0, 0, 0, 0};
}

// ---- degree histogram, dst-range partitioned (XCD-local atomic lines) ----
__global__ void deg_part_kernel(const int* __restrict__ dst, int* __restrict__ deg,
                                int E, int N) {
    const int g = blockIdx.x & 7;
    const int per = (N + 7) / 8;
    const int lo = g * per;
    const int hi = min(N, lo + per);
    const int nb = gridDim.x >> 3;
    const int b = blockIdx.x >> 3;
    for (int e = b * blockDim.x + threadIdx.x; e < E; e += nb * blockDim.x) {
        int d = dst[e];
        if (d >= lo && d < hi) atomicAdd(&deg[d], 1);
    }
}

// ---- per-block local exclusive scan of deg ----
__global__ __launch_bounds__(1024) void scanA_kernel(const int* __restrict__ deg,
                                                     int* __restrict__ excl,
                                                     int* __restrict__ bsum, int N) {
    const int tid = threadIdx.x, lane = tid & 63, wid = tid >> 6;
    const int i = blockIdx.x * 1024 + tid;
    int v = (i < N) ? deg[i] : 0;
    int s = v;
#pragma unroll
    for (int off = 1; off < 64; off <<= 1) {
        int t = __shfl_up(s, off, 64);
        if (lane >= off) s += t;
    }
    __shared__ int wtot[16], woff[16];
    if (lane == 63) wtot[wid] = s;
    __syncthreads();
    if (wid == 0 && lane < 16) {
        int t = wtot[lane];
        int ss = t;
#pragma unroll
        for (int off = 1; off < 16; off <<= 1) {
            int u = __shfl_up(ss, off, 64);
            if (lane >= off) ss += u;
        }
        woff[lane] = ss - t;
        if (lane == 15) bsum[blockIdx.x] = ss;
    }
    __syncthreads();
    if (i < N) excl[i] = woff[wid] + (s - v);
}

// ---- apply: scans bsum (NB<=64) in-wave per block ----
__global__ __launch_bounds__(1024) void scanC_kernel(const int* __restrict__ excl,
                                                     const int* __restrict__ bsum,
                                                     const int* __restrict__ deg,
                                                     int* __restrict__ row_start,
                                                     int* __restrict__ cursor,
                                                     float* __restrict__ inv_deg,
                                                     int N, int E, int NB) {
    __shared__ int boff_s;
    const int tid = threadIdx.x;
    if (tid < 64) {
        int lane = tid;
        int v = (lane < NB) ? bsum[lane] : 0;
        int s = v;
#pragma unroll
        for (int off = 1; off < 64; off <<= 1) {
            int t = __shfl_up(s, off, 64);
            if (lane >= off) s += t;
        }
        if (lane == (int)blockIdx.x) boff_s = s - v;
    }
    __syncthreads();
    const int boff = boff_s;
    int i = blockIdx.x * 1024 + tid;
    if (i < N) {
        int e = excl[i] + boff;
        row_start[i] = e;
        cursor[i] = e;
        int d = deg[i];
        inv_deg[i] = (d > 0) ? 1.0f / (float)d : 0.0f;
    }
    if (blockIdx.x == 0 && tid == 0) row_start[N] = E;
}

// ---- CSR fill, dst-range partitioned ----
__global__ void fill_part_kernel(const int* __restrict__ src, const int* __restrict__ dst,
                                 int* __restrict__ cursor, int* __restrict__ csr,
                                 int E, int N) {
    const int g = blockIdx.x & 7;
    const int per = (N + 7) / 8;
    const int lo = g * per;
    const int hi = min(N, lo + per);
    const int nb = gridDim.x >> 3;
    const int b = blockIdx.x >> 3;
    for (int e = b * blockDim.x + threadIdx.x; e < E; e += nb * blockDim.x) {
        int d = dst[e];
        if (d >= lo && d < hi) {
            int p = atomicAdd(&cursor[d], 1);
            csr[p] = src[e];
        }
    }
}

// ---- aggregate: wave per node, 4 lane-groups x 16 lanes; group handles one
// neighbor per step, lane covers 4 dims (ushort4). One load instruction fetches
// 4 neighbor rows -> ~5 VMEM/node vs ~17 in the per-dim layout (round-9 was
// VMEM-issue bound). Cross-group combine: shfl_xor 16/32 once per node. ----
__global__ __launch_bounds__(256, 8) void agg_kernel(
    const ushort* __restrict__ hb, const int* __restrict__ row_start,
    const int* __restrict__ csr, const float* __restrict__ inv_deg,
    ushort* __restrict__ neighb, int N) {
    const int wv = (blockIdx.x * blockDim.x + threadIdx.x) >> 6;
    const int lane = threadIdx.x & 63;
    if (wv >= N) return;
    const int rs = row_start[wv];
    const int re = row_start[wv + 1];
    const int grp = lane >> 4;          // neighbor slot 0..3 within a step
    const int sub = (lane & 15) << 2;   // feature dims sub..sub+3

    float a0 = 0.f, a1 = 0.f, a2 = 0.f, a3 = 0.f;
    float b0 = 0.f, b1 = 0.f, b2 = 0.f, b3 = 0.f;
    int j = rs;
    while (j < re) {
        int take = re - j;
        if (take > 64) take = 64;
        int idx = (lane < take) ? csr[j + lane] : 0;   // one coalesced index load
        int i = 0;
        for (; i + 8 <= take; i += 8) {                // 8 neighbors: 2 loads/lane
            int s0 = __shfl(idx, i + grp, 64);
            int s1 = __shfl(idx, i + 4 + grp, 64);
            ushort4 v0 = *(const ushort4*)&hb[(long long)s0 * HD + sub];
            ushort4 v1 = *(const ushort4*)&hb[(long long)s1 * HD + sub];
            a0 += bf2f(v0.x); a1 += bf2f(v0.y); a2 += bf2f(v0.z); a3 += bf2f(v0.w);
            b0 += bf2f(v1.x); b1 += bf2f(v1.y); b2 += bf2f(v1.z); b3 += bf2f(v1.w);
        }
        for (; i < take; i += 4) {                     // tail (<8 neighbors)
            int p = i + grp;
            int s = __shfl(idx, p < take ? p : 0, 64);
            if (p < take) {
                ushort4 v = *(const ushort4*)&hb[(long long)s * HD + sub];
                a0 += bf2f(v.x); a1 += bf2f(v.y); a2 += bf2f(v.z); a3 += bf2f(v.w);
            }
        }
        j += take;
    }
    a0 += b0; a1 += b1; a2 += b2; a3 += b3;
    // combine the 4 groups (lanes l, l^16, l^32, l^48 hold the same dims)
    a0 += __shfl_xor(a0, 16, 64); a0 += __shfl_xor(a0, 32, 64);
    a1 += __shfl_xor(a1, 16, 64); a1 += __shfl_xor(a1, 32, 64);
    a2 += __shfl_xor(a2, 16, 64); a2 += __shfl_xor(a2, 32, 64);
    a3 += __shfl_xor(a3, 16, 64); a3 += __shfl_xor(a3, 32, 64);
    if (grp == 0) {
        float inv = inv_deg[wv];
        ushort4 o;
        o.x = f2bf(a0 * inv); o.y = f2bf(a1 * inv);
        o.z = f2bf(a2 * inv); o.w = f2bf(a3 * inv);
        *(ushort4*)&neighb[(long long)wv * HD + sub] = o;
    }
}

// ---- MFMA GEMM + relu + L2-norm: out = l2norm(relu([hb|neighb] @ Wb^T)) ----
// 256 thr / 4 waves; wave owns 16 nodes, all 64 out dims. A/B frags straight
// from global (L2-hit), no LDS. C/D layout: col=lane&15, row=(lane>>4)*4+reg.
__global__ __launch_bounds__(256) void gemm_mfma_kernel(
    const ushort* __restrict__ hb, const ushort* __restrict__ nbf,
    const ushort* __restrict__ Wb, float* __restrict__ out,
    ushort* __restrict__ hb_out, int N, int last) {
    const int lane = threadIdx.x & 63;
    const int w = threadIdx.x >> 6;
    const int base = blockIdx.x * 64 + w * 16;
    const int m = lane & 15;          // A row / B col within tile
    const int kq = lane >> 4;         // k-quad
    int anode = base + m;
    if (anode > N - 1) anode = N - 1; // clamp (reads only; stores guarded)
    const long long arow = (long long)anode * HD;

    f32x4 acc[4] = {{0.f,0.f,0.f,0.f},{0.f,0.f,0.f,0.f},{0.f,0.f,0.f,0.f},{0.f,0.f,0.f,0.f}};
#pragma unroll
    for (int kk = 0; kk < 4; ++kk) {
        const ushort* ap = (kk < 2 ? hb : nbf) + arow + (kk & 1) * 32 + kq * 8;
        bf16x8 a = *(const bf16x8*)ap;
        const ushort* bp = Wb + (long long)m * 128 + kk * 32 + kq * 8;
#pragma unroll
        for (int t = 0; t < 4; ++t) {
            bf16x8 b = *(const bf16x8*)(bp + (long long)t * 16 * 128);
            acc[t] = __builtin_amdgcn_mfma_f32_16x16x32_bf16(a, b, acc[t], 0, 0, 0);
        }
    }

    float sq[4] = {0.f, 0.f, 0.f, 0.f};
#pragma unroll
    for (int t = 0; t < 4; ++t)
#pragma unroll
        for (int r = 0; r < 4; ++r) {
            float v = fmaxf(acc[t][r], 0.f);
            acc[t][r] = v;
            sq[r] += v * v;
        }
#pragma unroll
    for (int off = 1; off < 16; off <<= 1)
#pragma unroll
        for (int r = 0; r < 4; ++r) sq[r] += __shfl_xor(sq[r], off, 64);

    float scl[4];
#pragma unroll
    for (int r = 0; r < 4; ++r) scl[r] = 1.f / fmaxf(sqrtf(sq[r]), 1e-12f);

    if (last) {
#pragma unroll
        for (int r = 0; r < 4; ++r) {
            int node = base + kq * 4 + r;
            if (node < N) {
#pragma unroll
                for (int t = 0; t < 4; ++t)
                    out[(long long)node * HD + t * 16 + m] = acc[t][r] * scl[r];
            }
        }
    } else {
#pragma unroll
        for (int r = 0; r < 4; ++r) {
            int node = base + kq * 4 + r;
            if (node < N) {
#pragma unroll
                for (int t = 0; t < 4; ++t)
                    hb_out[(long long)node * HD + t * 16 + m] = f2bf(acc[t][r] * scl[r]);
            }
        }
    }
}

extern "C" void kernel_launch(void* const* d_in, const int* in_sizes, int n_in,
                              void* d_out, int out_size, void* d_ws, size_t ws_size,
                              hipStream_t stream) {
    const float* x    = (const float*)d_in[0];
    const float* W    = (const float*)d_in[1];
    const int*   esrc = (const int*)d_in[2];
    const int*   edst = (const int*)d_in[3];
    float* out = (float*)d_out;

    const int N = in_sizes[0] / HD;
    const int E = in_sizes[2];
    const int DEPTH = in_sizes[1] / (HD * 2 * HD);
    const int NB = (N + 1023) / 1024;

    // ws: deg | excl | bsum | row_start | cursor | inv_deg | csr | hb0 | hb1 | neighb | Wb
    auto align256 = [](size_t v) { return (v + 255) & ~(size_t)255; };
    char* ws = (char*)d_ws;
    int*    deg       = (int*)ws;     ws += align256((size_t)(N + 8) * 4);
    int*    excl      = (int*)ws;     ws += align256((size_t)N * 4);
    int*    bsum      = (int*)ws;     ws += align256(64 * 4);
    int*    row_start = (int*)ws;     ws += align256((size_t)(N + 1) * 4);
    int*    cursor    = (int*)ws;     ws += align256((size_t)N * 4);
    float*  inv_deg   = (float*)ws;   ws += align256((size_t)N * 4);
    int*    csr       = (int*)ws;     ws += align256((size_t)E * 4);
    ushort* hb0       = (ushort*)ws;  ws += align256((size_t)N * HD * 2);
    ushort* hb1       = (ushort*)ws;  ws += align256((size_t)N * HD * 2);
    ushort* neighb    = (ushort*)ws;  ws += align256((size_t)N * HD * 2);
    ushort* Wb        = (ushort*)ws;

    // fused prep: x->bf16, W->bf16, deg=0
    int xn4 = N * HD / 4;
    int wn4 = DEPTH * HD * 2 * HD / 4;
    int dn4 = (N + 3) / 4;
    int ptot = xn4 + wn4 + dn4;
    prep_kernel<<<(ptot + 255) / 256, 256, 0, stream>>>(
        (const float4*)x, (ushort4*)hb0, xn4,
        (const float4*)W, (ushort4*)Wb, wn4,
        (int4*)deg, dn4);

    deg_part_kernel<<<2048, 256, 0, stream>>>(edst, deg, E, N);
    scanA_kernel<<<NB, 1024, 0, stream>>>(deg, excl, bsum, N);
    scanC_kernel<<<NB, 1024, 0, stream>>>(excl, bsum, deg, row_start, cursor, inv_deg, N, E, NB);
    fill_part_kernel<<<2048, 256, 0, stream>>>(esrc, edst, cursor, csr, E, N);

    ushort* hb_cur = hb0;
    ushort* hb_nxt = hb1;
    for (int k = 0; k < DEPTH; ++k) {
        int last = (k == DEPTH - 1) ? 1 : 0;
        agg_kernel<<<(N * 64 + 255) / 256, 256, 0, stream>>>(hb_cur, row_start, csr,
                                                             inv_deg, neighb, N);
        gemm_mfma_kernel<<<(N + 63) / 64, 256, 0, stream>>>(hb_cur, neighb,
                                                            Wb + (size_t)k * HD * 2 * HD,
                                                            out, hb_nxt, N, last);
        ushort* t = hb_cur; hb_cur = hb_nxt; hb_nxt = t;
    }
}